// Round 5
// baseline (280.222 us; speedup 1.0000x reference)
//
#include <hip/hip_runtime.h>

#define DIM 4096
// SCALE = 1/sqrt(4096) = 1/64: exact power of two -> multiplication is exact,
// so folding it into the gauss factor is bitwise-identical to the reference.
#define FF_SCALE 0.015625f
#define LDST 68  // padded leading dim: 64 + 4

// Padded LDS layout: logical float index i lives at dword addr i + 4*(i>>6).
// For j = l + 64c this is l + 68c: strided phases have lane-varying addresses
// (2 lanes/bank = free) with vaddr=l and pure-immediate offsets (272c bytes).
// Contiguous phases (lane l owns 64l..64l+63) write b128 at 68l+4q: quad-slot
// (17l+q)%8 = (l+q)%8 -> even 8-lane spread = structural-optimal b128.
__device__ __forceinline__ int pad(int i) { return i + ((i >> 6) << 2); }

// 64-point unnormalized FWHT, ascending stage order h=1..32 (matches ref).
__device__ __forceinline__ void fwht64(float v[64]) {
#pragma unroll
    for (int h = 1; h < 64; h <<= 1) {
#pragma unroll
        for (int i = 0; i < 64; ++i) {
            if ((i & h) == 0) {
                float a = v[i], b = v[i + h];
                v[i] = a + b;
                v[i + h] = a - b;
            }
        }
    }
}

// ONE WAVE PER ROW. Zero cross-wave synchronization: the block is a single
// wave, its LDS slab is wave-private, and every __syncthreads() is a
// single-wave barrier (an lgkmcnt drain; no inter-wave lock-step).
// FWHT(4096) = fwht64 over low bits (lane holds i=64l+e contiguous)
//            o LDS transpose
//            o fwht64 over high bits (lane holds i=l+64c strided).
// Global stage order is ascending h=1..2048 -> identical butterfly tree to
// the reference implementation.
__global__ __launch_bounds__(64) void fastfood_kernel(
    const float* __restrict__ x,
    const float* __restrict__ d1,
    const float* __restrict__ d2,
    const float* __restrict__ gauss_d,
    const int* __restrict__ perm,
    float* __restrict__ out)
{
    __shared__ float slab[64 * LDST];  // 17408 B -> 9 blocks(waves)/CU
    const int l = threadIdx.x;         // lane 0..63
    const size_t rowoff = (size_t)blockIdx.x * DIM;

    float v[64];

    // ---- load x*d1: lane l holds contiguous i = 64l+e (16x float4) ----
    {
        const float4* xv = (const float4*)(x + rowoff + l * 64);
        const float4* dv = (const float4*)(d1 + l * 64);
#pragma unroll
        for (int q = 0; q < 16; ++q) {
            float4 a = xv[q], d = dv[q];
            v[4 * q + 0] = a.x * d.x;
            v[4 * q + 1] = a.y * d.y;
            v[4 * q + 2] = a.z * d.z;
            v[4 * q + 3] = a.w * d.w;
        }
    }

    // ---- FWHT1 low stages h=1..32 (in-register) ----
    fwht64(v);

    // ---- transpose: contiguous b128 writes ----
    {
        float* wp = slab + l * LDST;
#pragma unroll
        for (int q = 0; q < 16; ++q)
            *(float4*)(wp + 4 * q) =
                make_float4(v[4 * q], v[4 * q + 1], v[4 * q + 2], v[4 * q + 3]);
    }
    __syncthreads();  // single-wave: lgkm drain only

    // ---- FWHT1 high stages h=64..2048: lane l holds j = l+64c ----
#pragma unroll
    for (int c = 0; c < 64; ++c) v[c] = slab[l + LDST * c];
    fwht64(v);
    // write FWHT1 result back (same addresses this lane just read)
#pragma unroll
    for (int c = 0; c < 64; ++c) slab[l + LDST * c] = v[c];
    __syncthreads();  // full FWHT1 row visible to all lanes

    // ---- permutation gather + gauss*SCALE: lane l gathers j = 64l+e ----
    {
        const int4* pv = (const int4*)(perm + l * 64);
        const float4* gv = (const float4*)(gauss_d + l * 64);
#pragma unroll
        for (int q = 0; q < 16; ++q) {
            int4 p4 = pv[q];
            float4 g4 = gv[q];
            // gauss*SCALE first: exact (pow2), matches reference rounding
            v[4 * q + 0] = slab[pad(p4.x)] * (g4.x * FF_SCALE);
            v[4 * q + 1] = slab[pad(p4.y)] * (g4.y * FF_SCALE);
            v[4 * q + 2] = slab[pad(p4.z)] * (g4.z * FF_SCALE);
            v[4 * q + 3] = slab[pad(p4.w)] * (g4.w * FF_SCALE);
        }
    }

    // ---- FWHT2 low stages h=1..32 (in-register; overlaps nothing to wait) --
    fwht64(v);
    __syncthreads();  // all lanes' gather reads done before slab overwrite

    // ---- transpose ----
    {
        float* wp = slab + l * LDST;
#pragma unroll
        for (int q = 0; q < 16; ++q)
            *(float4*)(wp + 4 * q) =
                make_float4(v[4 * q], v[4 * q + 1], v[4 * q + 2], v[4 * q + 3]);
    }
    __syncthreads();

    // ---- FWHT2 high stages + fused d2 epilogue ----
#pragma unroll
    for (int c = 0; c < 64; ++c) v[c] = slab[l + LDST * c];
    fwht64(v);
    {
        const float* d2p = d2 + l;
        float* op = out + rowoff + l;
        // per c: 64 lanes store 256 contiguous bytes -> fully coalesced
#pragma unroll
        for (int c = 0; c < 64; ++c)
            op[64 * c] = v[c] * d2p[64 * c];  // SCALE folded at gather
    }
}

extern "C" void kernel_launch(void* const* d_in, const int* in_sizes, int n_in,
                              void* d_out, int out_size, void* d_ws, size_t ws_size,
                              hipStream_t stream) {
    const float* x       = (const float*)d_in[0];
    const float* d1      = (const float*)d_in[1];
    const float* d2      = (const float*)d_in[2];
    const float* gauss_d = (const float*)d_in[3];
    const int*   perm    = (const int*)d_in[4];
    float* out = (float*)d_out;

    const int batch = in_sizes[0] / DIM;  // 8192
    fastfood_kernel<<<batch, 64, 0, stream>>>(x, d1, d2, gauss_d, perm, out);
}

// Round 6
// 253.091 us; speedup vs baseline: 1.1072x; 1.1072x over previous
//
#include <hip/hip_runtime.h>

#define DIM 4096
// SCALE = 1/sqrt(4096) = 1/64: exact power of two, so folding it into the
// gauss factor before FWHT2 is bitwise-identical to the reference (scaling
// by 2^-6 commutes exactly with adds/muls; no denormals at these magnitudes).
#define FF_SCALE 0.015625f

typedef __attribute__((ext_vector_type(2))) float f32x2;

// Packed dual-FP32 ops (VOP3P). gfx950 has these: the 157.3 TF fp32 spec
// equals 256CU x 64lane x 2.4GHz x 2(fma) x 2(pk). Rounding of each half is
// identical to scalar v_add_f32 -> bitwise-identical butterfly results.
__device__ __forceinline__ f32x2 pk_add(f32x2 a, f32x2 b) {
    f32x2 d;
    asm("v_pk_add_f32 %0, %1, %2" : "=v"(d) : "v"(a), "v"(b));
    return d;
}
__device__ __forceinline__ f32x2 pk_sub(f32x2 a, f32x2 b) {
    f32x2 d;
    asm("v_pk_add_f32 %0, %1, %2 neg_lo:[0,1] neg_hi:[0,1]"
        : "=v"(d) : "v"(a), "v"(b));
    return d;
}
__device__ __forceinline__ f32x2 pk_mul(f32x2 a, f32x2 b) {
    f32x2 d;
    asm("v_pk_mul_f32 %0, %1, %2" : "=v"(d) : "v"(a), "v"(b));
    return d;
}

// 16-point FWHT on 8 packed pairs p[m] = (v[2m], v[2m+1]), ascending
// stage order h=1,2,4,8 (identical butterfly tree to the reference).
// h=1 is within-pair (scalar adds); h=2,4,8 are pair-wise packed: 2 adds/op.
__device__ __forceinline__ void fwht16_pk(f32x2 p[8]) {
#pragma unroll
    for (int m = 0; m < 8; ++m) {
        float a = p[m].x, b = p[m].y;
        p[m].x = a + b;
        p[m].y = a - b;
    }
#pragma unroll
    for (int h2 = 1; h2 < 8; h2 <<= 1) {
#pragma unroll
        for (int m = 0; m < 8; ++m)
            if ((m & h2) == 0) {
                f32x2 a = p[m], b = p[m + h2];
                p[m] = pk_add(a, b);
                p[m + h2] = pk_sub(a, b);
            }
    }
}

// LDS layout: logical float index i lives at dword addr i + 4*(i>>8)
// (each 256-float block shifted by 4 dwords).
//  - R2 (stride-16 within a block): bank = (4a+16b+c)%32 -> max 4-way on a
//    few banks, ~2.3 avg (vs uniform 4-way unpadded); pairs (b,b+1) are 16
//    dwords apart with base+240 max -> compiler merges to ds_read2_b32
//    straight into the packed f32x2 pair.
//  - R3 (stride-256): bank = (4a+t)%32, per-instr a fixed -> conflict-free.
//  - R1 b64 writes: ~2-way (free).
__device__ __forceinline__ int padidx(int i) { return i + ((i >> 8) << 2); }

// One block per row, 256 threads (4 waves), radix-16^3 per FWHT (r1 skeleton):
//  R1: thread t owns contig i=16t+j   (stages h=1..8)
//  R2: thread t owns i=256a+16b+c, a=t>>4, c=t&15 (stages h=16..128)
//  R3: thread t owns i=256a+t         (stages h=256..2048)
__global__ __launch_bounds__(256, 8) void fastfood_kernel(
    const float* __restrict__ x,
    const float* __restrict__ d1,
    const float* __restrict__ d2,
    const float* __restrict__ gauss_d,
    const int* __restrict__ perm,
    float* __restrict__ out)
{
    __shared__ float lds[DIM + 64];  // 16.6 KB -> 8 blocks/CU (32 waves)
    const int t = threadIdx.x;
    const size_t rowoff = (size_t)blockIdx.x * DIM;

    const int base_r1 = 16 * t + ((t >> 4) << 2);        // padidx(16t)
    const int base_r2 = 260 * (t >> 4) + (t & 15);       // padidx(256a + c)

    f32x2 p[8];

    // ---- load x*d1 (contiguous float4, coalesced) ----
    {
        const float4* xv = (const float4*)(x + rowoff + t * 16);
        const float4* dv = (const float4*)(d1 + t * 16);
#pragma unroll
        for (int q = 0; q < 4; ++q) {
            float4 aa = xv[q], dd = dv[q];
            p[2 * q]     = pk_mul((f32x2){aa.x, aa.y}, (f32x2){dd.x, dd.y});
            p[2 * q + 1] = pk_mul((f32x2){aa.z, aa.w}, (f32x2){dd.z, dd.w});
        }
    }

    // ---- FWHT1 R1: h=1..8 ----
    fwht16_pk(p);
#pragma unroll
    for (int m = 0; m < 8; ++m)
        *(f32x2*)(lds + base_r1 + 2 * m) = p[m];   // ds_write_b64
    __syncthreads();  // B1

    // ---- FWHT1 R2: h=16..128 (pairs along b via ds_read2_b32) ----
#pragma unroll
    for (int m = 0; m < 8; ++m) {
        f32x2 w;
        w.x = lds[base_r2 + 32 * m];
        w.y = lds[base_r2 + 32 * m + 16];
        p[m] = w;
    }
    fwht16_pk(p);
#pragma unroll
    for (int m = 0; m < 8; ++m) {
        lds[base_r2 + 32 * m]      = p[m].x;
        lds[base_r2 + 32 * m + 16] = p[m].y;
    }
    __syncthreads();  // B2

    // ---- FWHT1 R3: h=256..2048 (pairs along a; conflict-free banks) ----
#pragma unroll
    for (int m = 0; m < 8; ++m) {
        f32x2 w;
        w.x = lds[t + 520 * m];
        w.y = lds[t + 520 * m + 260];
        p[m] = w;
    }
    fwht16_pk(p);
#pragma unroll
    for (int m = 0; m < 8; ++m) {
        lds[t + 520 * m]       = p[m].x;
        lds[t + 520 * m + 260] = p[m].y;
    }
    __syncthreads();  // B3: full FWHT1 row in LDS

    // ---- permutation gather + gauss*SCALE (FWHT2 input, contig 16t+k) ----
    {
        const int4* pv = (const int4*)(perm + t * 16);
        const float4* gv = (const float4*)(gauss_d + t * 16);
#pragma unroll
        for (int q = 0; q < 4; ++q) {
            int4 p4 = pv[q];
            float4 g4 = gv[q];
            f32x2 lo, hi;
            lo.x = lds[padidx(p4.x)];
            lo.y = lds[padidx(p4.y)];
            hi.x = lds[padidx(p4.z)];
            hi.y = lds[padidx(p4.w)];
            // gauss*SCALE first: exact (pow2), matches reference rounding
            f32x2 gs0 = pk_mul((f32x2){g4.x, g4.y}, (f32x2){FF_SCALE, FF_SCALE});
            f32x2 gs1 = pk_mul((f32x2){g4.z, g4.w}, (f32x2){FF_SCALE, FF_SCALE});
            p[2 * q]     = pk_mul(lo, gs0);
            p[2 * q + 1] = pk_mul(hi, gs1);
        }
    }

    // ---- FWHT2 R1 (register-only) ----
    fwht16_pk(p);
    __syncthreads();  // B4: all gather reads done before slab overwrite
#pragma unroll
    for (int m = 0; m < 8; ++m)
        *(f32x2*)(lds + base_r1 + 2 * m) = p[m];
    __syncthreads();  // B5

    // ---- FWHT2 R2 ----
#pragma unroll
    for (int m = 0; m < 8; ++m) {
        f32x2 w;
        w.x = lds[base_r2 + 32 * m];
        w.y = lds[base_r2 + 32 * m + 16];
        p[m] = w;
    }
    fwht16_pk(p);
#pragma unroll
    for (int m = 0; m < 8; ++m) {
        lds[base_r2 + 32 * m]      = p[m].x;
        lds[base_r2 + 32 * m + 16] = p[m].y;
    }
    __syncthreads();  // B6

    // ---- FWHT2 R3 + fused d2 epilogue (SCALE already folded) ----
#pragma unroll
    for (int m = 0; m < 8; ++m) {
        f32x2 w;
        w.x = lds[t + 520 * m];
        w.y = lds[t + 520 * m + 260];
        p[m] = w;
    }
    fwht16_pk(p);
    {
        const float* d2p = d2 + t;
        float* op = out + rowoff + t;
        // per store instr: 64 lanes write 256 contiguous bytes -> coalesced
#pragma unroll
        for (int m = 0; m < 8; ++m) {
            f32x2 dd;
            dd.x = d2p[512 * m];
            dd.y = d2p[512 * m + 256];
            f32x2 r = pk_mul(p[m], dd);
            op[512 * m]       = r.x;
            op[512 * m + 256] = r.y;
        }
    }
}

extern "C" void kernel_launch(void* const* d_in, const int* in_sizes, int n_in,
                              void* d_out, int out_size, void* d_ws, size_t ws_size,
                              hipStream_t stream) {
    const float* x       = (const float*)d_in[0];
    const float* d1      = (const float*)d_in[1];
    const float* d2      = (const float*)d_in[2];
    const float* gauss_d = (const float*)d_in[3];
    const int*   perm    = (const int*)d_in[4];
    float* out = (float*)d_out;

    const int batch = in_sizes[0] / DIM;  // 8192
    fastfood_kernel<<<batch, 256, 0, stream>>>(x, d1, d2, gauss_d, perm, out);
}